// Round 13
// baseline (327.528 us; speedup 1.0000x reference)
//
#include <hip/hip_runtime.h>
#include <cstdint>

#define EPSF 1e-5f
constexpr int KOFF = 27;

typedef __attribute__((ext_vector_type(8))) short bf16x8;
typedef __attribute__((ext_vector_type(4))) float f32x4;
typedef unsigned short ushort_t;
typedef unsigned int uint_t;

// f32 -> bf16 bits, RNE
__device__ __forceinline__ ushort_t f2b(float f) {
    uint_t u = __float_as_uint(f);
    u += 0x7fffu + ((u >> 16) & 1u);
    return (ushort_t)(u >> 16);
}
// bf16 bits -> f32
__device__ __forceinline__ float b2f(ushort_t u) {
    return __uint_as_float(((uint_t)u) << 16);
}
// uint4 (8 packed bf16) -> 8 floats
__device__ __forceinline__ void u4tof(uint4 u, float* f) {
    uint_t w[4] = {u.x, u.y, u.z, u.w};
#pragma unroll
    for (int i = 0; i < 4; ++i) {
        f[2 * i]     = __uint_as_float(w[i] << 16);
        f[2 * i + 1] = __uint_as_float(w[i] & 0xffff0000u);
    }
}

__device__ __forceinline__ void gload_lds16(const void* g, float* l) {
    __builtin_amdgcn_global_load_lds(
        (const __attribute__((address_space(1))) void*)g,
        (__attribute__((address_space(3))) void*)l, 16, 0, 0);
}

// ---------------------------------------------------------------------------
// f32 -> bf16 convert, 8 elems/thread.
// ---------------------------------------------------------------------------
__global__ __launch_bounds__(256) void cvt_k(const float* __restrict__ in,
                                             ushort_t* __restrict__ out, int n8) {
    int i = blockIdx.x * 256 + threadIdx.x;
    if (i >= n8) return;
    float4 a = ((const float4*)in)[2 * i];
    float4 b = ((const float4*)in)[2 * i + 1];
    uint4 o;
    o.x = (uint_t)f2b(a.x) | ((uint_t)f2b(a.y) << 16);
    o.y = (uint_t)f2b(a.z) | ((uint_t)f2b(a.w) << 16);
    o.z = (uint_t)f2b(b.x) | ((uint_t)f2b(b.y) << 16);
    o.w = (uint_t)f2b(b.z) | ((uint_t)f2b(b.w) << 16);
    ((uint4*)out)[i] = o;
}

// W [27][CIN][64] f32 -> Wt [27][64][CIN] bf16
__global__ __launch_bounds__(256) void wtT_k(const float* __restrict__ W,
                                             ushort_t* __restrict__ Wt, int CIN) {
    int t     = blockIdx.x * 256 + threadIdx.x;
    int total = KOFF * CIN * 64;
    if (t >= total) return;
    int o    = t & 63;
    int rest = t >> 6;
    int i    = rest % CIN;
    int k    = rest / CIN;
    Wt[((size_t)k * 64 + o) * CIN + i] = f2b(W[t]);
}

// lin_w [32][64] f32 -> lin_wt [64][32] bf16
__global__ __launch_bounds__(256) void linT_k(const float* __restrict__ lw,
                                              ushort_t* __restrict__ wt) {
    int t = blockIdx.x * 256 + threadIdx.x;
    if (t >= 64 * 32) return;
    int o = t >> 5, i = t & 31;
    wt[o * 32 + i] = f2b(lw[i * 64 + o]);
}

// ---------------------------------------------------------------------------
// MFMA gather conv, PHASE-pipelined (R10 config — verified 67 us, at the
// ~2.3 TB/s random-gather service ceiling). 256 thr / 64 rows / PH=2.
// STATS=true additionally emits per-block per-channel sum/sumsq of the
// bf16-rounded outputs (replaces the separate statsb1 pass).
// ---------------------------------------------------------------------------
template <int CIN, bool STATS>
__global__ __launch_bounds__(256, 6) void convm_k(
    const ushort_t* __restrict__ feats,  // [N][CIN] bf16
    const int* __restrict__ nbr,         // [N][27]
    const ushort_t* __restrict__ Wt,     // [27][64][CIN] bf16
    ushort_t* __restrict__ outp,         // [N][64] bf16
    float* __restrict__ part,            // [nblocks][128] (STATS only)
    int N) {
    constexpr int CHUNKS = CIN / 8;
    constexpr int T      = CIN / 32;
    constexpr int NS     = CHUNKS / 4;
    constexpr int M      = CHUNKS - 1;
    constexpr int PH     = 2;
    constexpr int NPH    = (KOFF + PH - 1) / PH;  // 14 (last = 1 step)

    __shared__ float lds[2][PH][64 * CHUNKS * 4];

    const int lane = threadIdx.x & 63;
    const int wv   = threadIdx.x >> 6;
    const int lo   = lane & 15;
    const int hi   = lane >> 4;
    const int row0 = blockIdx.x * 64;

    int srcoff[NS];
    const int* nbp[NS];
    int ldsbase[NS];
#pragma unroll
    for (int i = 0; i < NS; ++i) {
        int c      = (wv * NS + i) * 64 + lane;
        int r      = c / CHUNKS;
        int ch     = c & M;
        srcoff[i]  = (ch ^ (r & M)) * 8;
        int grow   = row0 + r;
        if (grow >= N) grow = N - 1;
        nbp[i]     = nbr + (size_t)grow * KOFF;
        ldsbase[i] = (wv * NS + i) * 256;
    }

    f32x4 acc[4] = {{0.f, 0.f, 0.f, 0.f},
                    {0.f, 0.f, 0.f, 0.f},
                    {0.f, 0.f, 0.f, 0.f},
                    {0.f, 0.f, 0.f, 0.f}};

    int idxb[2][PH][NS];
    bf16x8 Bb[2][PH][T];

    auto NSTEPS = [&](int pp) { return (pp * PH + PH <= KOFF) ? PH : (KOFF - pp * PH); };

    auto LOADIDX = [&](int pp) {
        int ns = NSTEPS(pp);
#pragma unroll
        for (int s = 0; s < PH; ++s)
            if (s < ns)
#pragma unroll
                for (int i = 0; i < NS; ++i)
                    idxb[pp & 1][s][i] = nbp[i][pp * PH + s];
    };
    auto LOADB = [&](int pp) {
        int ns = NSTEPS(pp);
#pragma unroll
        for (int s = 0; s < PH; ++s)
            if (s < ns) {
                const ushort_t* wb =
                    Wt + ((size_t)(pp * PH + s) * 64 + wv * 16 + lo) * CIN + hi * 8;
#pragma unroll
                for (int t = 0; t < T; ++t)
                    Bb[pp & 1][s][t] = *(const bf16x8*)(wb + t * 32);
            }
    };
    auto STAGE = [&](int pp) {
        int ns = NSTEPS(pp);
#pragma unroll
        for (int s = 0; s < PH; ++s)
            if (s < ns)
#pragma unroll
                for (int i = 0; i < NS; ++i) {
                    const ushort_t* src =
                        feats + (size_t)idxb[pp & 1][s][i] * CIN + srcoff[i];
                    gload_lds16(src, &lds[pp & 1][s][ldsbase[i]]);
                }
    };

    LOADIDX(0);
    LOADIDX(1);
    LOADB(0);
    STAGE(0);
    __syncthreads();

#pragma unroll
    for (int p = 0; p < NPH; ++p) {
        if (p + 2 < NPH) LOADIDX(p + 2);
        if (p + 1 < NPH) {
            LOADB(p + 1);
            STAGE(p + 1);
        }
        __builtin_amdgcn_sched_barrier(0);
        int ns = NSTEPS(p);
#pragma unroll
        for (int s = 0; s < PH; ++s) {
            if (s < ns) {
#pragma unroll
                for (int mt = 0; mt < 4; ++mt) {
                    const int R = mt * 16 + lo;
#pragma unroll
                    for (int t = 0; t < T; ++t) {
                        int d    = t * 4 + hi;
                        int slot = d ^ (R & M);
                        bf16x8 a =
                            *(const bf16x8*)&lds[p & 1][s][(R * CHUNKS + slot) * 4];
                        acc[mt] = __builtin_amdgcn_mfma_f32_16x16x32_bf16(
                            a, Bb[p & 1][s][t], acc[mt], 0, 0, 0);
                    }
                }
            }
        }
        __syncthreads();
    }

    // C-write (+ optional fused per-block BN stats of the bf16 values).
    float s = 0.f, ss = 0.f;
#pragma unroll
    for (int mt = 0; mt < 4; ++mt) {
#pragma unroll
        for (int r = 0; r < 4; ++r) {
            int orow = row0 + mt * 16 + hi * 4 + r;
            if (orow < N) {
                ushort_t b = f2b(acc[mt][r]);
                outp[(size_t)orow * 64 + wv * 16 + lo] = b;
                if (STATS) {
                    float v = b2f(b);
                    s += v;
                    ss += v * v;
                }
            }
        }
    }
    if (STATS) {
        // Columns: wv*16+lo; the 4 hi-lanes of a column reduce via xor-shuffle.
        s  += __shfl_xor(s, 16);
        s  += __shfl_xor(s, 32);
        ss += __shfl_xor(ss, 16);
        ss += __shfl_xor(ss, 32);
        if (hi == 0) {
            part[(size_t)blockIdx.x * 128 + wv * 16 + lo]      = s;
            part[(size_t)blockIdx.x * 128 + 64 + wv * 16 + lo] = ss;
        }
    }
}

// ---------------------------------------------------------------------------
// BN stats stage 1 (f32 [n,32]): per-block partials, no atomics.
// ---------------------------------------------------------------------------
__global__ __launch_bounds__(256) void statsp1_k(const float* __restrict__ v,
                                                 int n, float* __restrict__ part) {
    __shared__ float ls[2 * 256];
    const int c = threadIdx.x & 31;
    int r0      = blockIdx.x * 8 + (threadIdx.x >> 5);
    int stride  = gridDim.x * 8;
    float s = 0.f, ss = 0.f;
    for (int r = r0; r < n; r += stride) {
        float x = v[(size_t)r * 32 + c];
        s += x;
        ss += x * x;
    }
    ls[threadIdx.x]       = s;
    ls[256 + threadIdx.x] = ss;
    __syncthreads();
    for (int off = 128; off >= 32; off >>= 1) {
        if (threadIdx.x < off) {
            ls[threadIdx.x] += ls[threadIdx.x + off];
            ls[256 + threadIdx.x] += ls[256 + threadIdx.x + off];
        }
        __syncthreads();
    }
    if (threadIdx.x < 32) {
        part[(size_t)blockIdx.x * 64 + threadIdx.x]      = ls[threadIdx.x];
        part[(size_t)blockIdx.x * 64 + 32 + threadIdx.x] = ls[256 + threadIdx.x];
    }
}

// Stage 2: out[c] = sum_g part[g][c].
__global__ __launch_bounds__(128) void statsr_k(const float* __restrict__ part,
                                                float* __restrict__ out,
                                                int G, int C2) {
    int c = threadIdx.x;
    if (c >= C2) return;
    float s = 0.f;
#pragma unroll 8
    for (int g = 0; g < G; ++g) s += part[(size_t)g * C2 + c];
    out[c] = s;
}

// BN(train)+SiLU in place over bf16 [N,64], 8 elems/thread.
__global__ __launch_bounds__(256) void bnsilub_k(ushort_t* __restrict__ h,
                                                 const float* __restrict__ stats,
                                                 const float* __restrict__ gamma,
                                                 const float* __restrict__ beta,
                                                 int total8, float invN) {
    int i8 = blockIdx.x * 256 + threadIdx.x;
    if (i8 >= total8) return;
    int c0  = (i8 * 8) & 63;
    uint4 u = ((const uint4*)h)[i8];
    float f[8];
    u4tof(u, f);
#pragma unroll
    for (int j = 0; j < 8; ++j) {
        int c     = c0 + j;
        float m   = stats[c] * invN;
        float var = stats[64 + c] * invN - m * m;
        float x   = (f[j] - m) * rsqrtf(var + EPSF) * gamma[c] + beta[c];
        f[j]      = x / (1.f + expf(-x));
    }
    uint4 o;
    o.x = (uint_t)f2b(f[0]) | ((uint_t)f2b(f[1]) << 16);
    o.y = (uint_t)f2b(f[2]) | ((uint_t)f2b(f[3]) << 16);
    o.z = (uint_t)f2b(f[4]) | ((uint_t)f2b(f[5]) << 16);
    o.w = (uint_t)f2b(f[6]) | ((uint_t)f2b(f[7]) << 16);
    ((uint4*)h)[i8] = o;
}

// ---------------------------------------------------------------------------
// Point branch: dedup BN+SiLU, MFMA linear, gather combine. Additionally
// writes z1b (bf16, bucket-permuted order via pslot) so the voxel-average
// pass can stream sequentially instead of random-gathering z1.
// ---------------------------------------------------------------------------
__global__ __launch_bounds__(256) void point_k(
    const ushort_t* __restrict__ x,      // [N,64] bf16
    const float* __restrict__ z_feats,   // [P,32]
    const float* __restrict__ interp_w,  // [P,8]
    const int* __restrict__ interp_idx,  // [P,8]
    const ushort_t* __restrict__ lin_wt, // [64][32] bf16
    const float* __restrict__ lin_b,     // [64]
    const float* __restrict__ pstats, const float* __restrict__ pgamma,
    const float* __restrict__ pbeta, const int* __restrict__ pslot,
    float* __restrict__ z1_out, ushort_t* __restrict__ z1b,
    int P, float invP) {
    __shared__ ushort_t pz[64 * 40];
    __shared__ float zl[64 * 68];

    const int lane = threadIdx.x & 63;
    const int wv   = threadIdx.x >> 6;
    const int lo   = lane & 15;
    const int hi   = lane >> 4;
    const int p0   = blockIdx.x * 64;

    {
        int pp = p0 + lane;
        if (pp >= P) pp = P - 1;
        const int cb      = wv;
        const float4* zr  = (const float4*)(z_feats + (size_t)pp * 32 + cb * 8);
        float4 z0 = zr[0], z1v = zr[1];
        float f[8] = {z0.x, z0.y, z0.z, z0.w, z1v.x, z1v.y, z1v.z, z1v.w};
        uint_t pk[4];
#pragma unroll
        for (int j2 = 0; j2 < 4; ++j2) {
            ushort_t lo16, hi16;
#pragma unroll
            for (int e = 0; e < 2; ++e) {
                int j     = j2 * 2 + e;
                int c     = cb * 8 + j;
                float m   = pstats[c] * invP;
                float var = pstats[32 + c] * invP - m * m;
                float zn  = (f[j] - m) * rsqrtf(var + EPSF) * pgamma[c] + pbeta[c];
                float pzv = zn / (1.f + expf(-zn));
                ushort_t b = f2b(pzv);
                if (e == 0) lo16 = b; else hi16 = b;
            }
            pk[j2] = (uint_t)lo16 | ((uint_t)hi16 << 16);
        }
        *(uint4*)&pz[lane * 40 + cb * 8] = make_uint4(pk[0], pk[1], pk[2], pk[3]);
    }
    __syncthreads();

    {
        bf16x8 a = *(const bf16x8*)&pz[(wv * 16 + lo) * 40 + hi * 8];
        f32x4 lacc[4];
#pragma unroll
        for (int nt = 0; nt < 4; ++nt) {
            bf16x8 b = *(const bf16x8*)(lin_wt + (size_t)(nt * 16 + lo) * 32 + hi * 8);
            lacc[nt] = __builtin_amdgcn_mfma_f32_16x16x32_bf16(
                a, b, (f32x4){0.f, 0.f, 0.f, 0.f}, 0, 0, 0);
        }
#pragma unroll
        for (int nt = 0; nt < 4; ++nt)
#pragma unroll
            for (int r = 0; r < 4; ++r)
                zl[(wv * 16 + hi * 4 + r) * 68 + nt * 16 + lo] = lacc[nt][r];
    }
    __syncthreads();

    const int p = p0 + lane;
    if (p >= P) return;
    const int wbase = __builtin_amdgcn_readfirstlane(wv * 16);

    const int4* iip   = (const int4*)(interp_idx + (size_t)p * 8);
    const float4* iwp = (const float4*)(interp_w + (size_t)p * 8);
    int4 ia = iip[0], ib = iip[1];
    float4 wa = iwp[0], wb = iwp[1];
    int idxs[8]  = {ia.x, ia.y, ia.z, ia.w, ib.x, ib.y, ib.z, ib.w};
    float wts[8] = {wa.x, wa.y, wa.z, wa.w, wb.x, wb.y, wb.z, wb.w};

    float acc[16];
#pragma unroll
    for (int o4 = 0; o4 < 4; ++o4) {
        f32x4 lv = *(const f32x4*)&zl[lane * 68 + wbase + o4 * 4];
#pragma unroll
        for (int j = 0; j < 4; ++j) acc[o4 * 4 + j] = lv[j];
    }

#pragma unroll
    for (int t = 0; t < 8; ++t) {
        const ushort_t* xr = x + (size_t)idxs[t] * 64 + wbase;
        float w            = wts[t];
        uint4 u0 = *(const uint4*)xr;
        uint4 u1 = *(const uint4*)(xr + 8);
        float f[16];
        u4tof(u0, f);
        u4tof(u1, f + 8);
#pragma unroll
        for (int o = 0; o < 16; ++o) acc[o] = fmaf(w, f[o], acc[o]);
    }

    const float* lb = lin_b + wbase;
#pragma unroll
    for (int o = 0; o < 16; ++o) acc[o] += lb[o];

    float* zo = z1_out + (size_t)p * 64 + wbase;
#pragma unroll
    for (int o = 0; o < 16; o += 4) {
        float4 v = {acc[o], acc[o + 1], acc[o + 2], acc[o + 3]};
        *(float4*)(zo + o) = v;
    }

    // bf16 copy in bucket-permuted order -> avg pass streams sequentially.
    int ps = pslot[p];
    uint_t pk[8];
#pragma unroll
    for (int j = 0; j < 8; ++j)
        pk[j] = (uint_t)f2b(acc[2 * j]) | ((uint_t)f2b(acc[2 * j + 1]) << 16);
    ushort_t* zb = z1b + (size_t)ps * 64 + wbase;
    *(uint4*)zb       = make_uint4(pk[0], pk[1], pk[2], pk[3]);
    *(uint4*)(zb + 8) = make_uint4(pk[4], pk[5], pk[6], pk[7]);
}

// --------------------------- CSR build + gather-average ---------------------
__global__ __launch_bounds__(256) void hist_k(const int* __restrict__ p2v,
                                              int* __restrict__ cnt, int P) {
    int p = blockIdx.x * 256 + threadIdx.x;
    if (p < P) atomicAdd(&cnt[p2v[p]], 1);
}

__global__ __launch_bounds__(256) void scan1_k(const int* __restrict__ cnt,
                                               int* __restrict__ tmp,
                                               int* __restrict__ bsum, int n) {
    __shared__ int s[256];
    int i = blockIdx.x * 256 + threadIdx.x;
    int v = (i < n) ? cnt[i] : 0;
    s[threadIdx.x] = v;
    __syncthreads();
    for (int off = 1; off < 256; off <<= 1) {
        int t = (threadIdx.x >= off) ? s[threadIdx.x - off] : 0;
        __syncthreads();
        s[threadIdx.x] += t;
        __syncthreads();
    }
    if (i < n) tmp[i] = s[threadIdx.x];
    if (threadIdx.x == 255) bsum[blockIdx.x] = s[255];
}

// Parallel single-block scan over <=512 block sums.
__global__ __launch_bounds__(512) void scan2_k(const int* __restrict__ bsum,
                                               int* __restrict__ bpre, int nb) {
    __shared__ int s[512];
    int i = threadIdx.x;
    int v = (i < nb) ? bsum[i] : 0;
    s[i]  = v;
    __syncthreads();
    for (int off = 1; off < 512; off <<= 1) {
        int t = (i >= off) ? s[i - off] : 0;
        __syncthreads();
        s[i] += t;
        __syncthreads();
    }
    if (i < nb) bpre[i] = s[i] - v;  // exclusive
}

__global__ __launch_bounds__(256) void scan3_k(const int* __restrict__ cnt,
                                               const int* __restrict__ tmp,
                                               const int* __restrict__ bpre,
                                               int* __restrict__ off, int n) {
    int i = blockIdx.x * 256 + threadIdx.x;
    if (i < n) off[i] = bpre[i >> 8] + tmp[i] - cnt[i];
}

// Also records pslot[p] = global bucket position of point p.
__global__ __launch_bounds__(256) void fill_k(const int* __restrict__ p2v,
                                              const int* __restrict__ off,
                                              int* __restrict__ cursor,
                                              int* __restrict__ pslot, int P) {
    int p = blockIdx.x * 256 + threadIdx.x;
    if (p >= P) return;
    int v    = p2v[p];
    int slot = atomicAdd(&cursor[v], 1);
    pslot[p] = off[v] + slot;
}

// x_new[v] = mean over rows [off[v], off[v]+cnt[v]) of z1b (sequential).
// Thread = (voxel, 16-channel quarter).
__global__ __launch_bounds__(256) void avg_k(const ushort_t* __restrict__ z1b,
                                             const int* __restrict__ off,
                                             const int* __restrict__ cnt,
                                             float* __restrict__ xnew, int N) {
    int tid = blockIdx.x * 256 + threadIdx.x;
    int v   = tid >> 2;
    if (v >= N) return;
    int q  = tid & 3;
    int c  = cnt[v];
    int st = off[v];
    float acc[16];
#pragma unroll
    for (int o = 0; o < 16; ++o) acc[o] = 0.f;
    for (int j = 0; j < c; ++j) {
        const ushort_t* zr = z1b + (size_t)(st + j) * 64 + q * 16;
        uint4 u0 = *(const uint4*)zr;
        uint4 u1 = *(const uint4*)(zr + 8);
        float f[16];
        u4tof(u0, f);
        u4tof(u1, f + 8);
#pragma unroll
        for (int o = 0; o < 16; ++o) acc[o] += f[o];
    }
    float rc  = 1.f / fmaxf((float)c, 1.f);
    float* op = xnew + (size_t)v * 64 + q * 16;
#pragma unroll
    for (int o = 0; o < 16; o += 4) {
        float4 t = {acc[o] * rc, acc[o + 1] * rc, acc[o + 2] * rc, acc[o + 3] * rc};
        *(float4*)(op + o) = t;
    }
}

extern "C" void kernel_launch(void* const* d_in, const int* in_sizes, int n_in,
                              void* d_out, int out_size, void* d_ws, size_t ws_size,
                              hipStream_t stream) {
    const float* x_feats   = (const float*)d_in[0];
    const float* z_feats   = (const float*)d_in[1];
    const float* interp_w  = (const float*)d_in[2];
    const int* nbr_idx     = (const int*)d_in[3];
    const int* interp_idx  = (const int*)d_in[4];
    const int* p2v_idx     = (const int*)d_in[5];
    const float* conv1_w   = (const float*)d_in[6];
    const float* conv2_w   = (const float*)d_in[7];
    const float* bn_gamma  = (const float*)d_in[8];
    const float* bn_beta   = (const float*)d_in[9];
    const float* pbn_gamma = (const float*)d_in[10];
    const float* pbn_beta  = (const float*)d_in[11];
    const float* lin_w     = (const float*)d_in[12];
    const float* lin_b     = (const float*)d_in[13];

    const int N  = in_sizes[3] / KOFF;   // 100000
    const int P  = in_sizes[5];          // 200000
    const int NB = (N + 255) / 256;
    const int GC = (N + 63) / 64;        // conv blocks (stats partials)
    const int GP = 256;

    // Workspace layout
    ushort_t* h2    = (ushort_t*)d_ws;                 // [N*64] bf16
    ushort_t* xb    = h2 + (size_t)N * 64;             // [N*64] bf16
    ushort_t* xf16  = xb + (size_t)N * 64;             // [N*32] bf16
    ushort_t* wt1   = xf16 + (size_t)N * 32;           // [27*64*32]
    ushort_t* wt2   = wt1 + KOFF * 64 * 32;            // [27*64*64]
    ushort_t* lwt   = wt2 + KOFF * 64 * 64;            // [64*32]
    int* cnt        = (int*)(lwt + 64 * 32);           // [N]
    int* cursor     = cnt + N;                         // [N]
    float* stats    = (float*)(cursor + N);            // [192]
    int* tmp        = (int*)(stats + 192);             // [N]
    int* off        = tmp + N;                         // [N]
    int* bsum       = off + N;                         // [512]
    int* bpre       = bsum + 512;                      // [512]
    int* pslot      = bpre + 512;                      // [P]
    ushort_t* z1b   = (ushort_t*)(pslot + P);          // [P*64] bf16
    float* part_h   = (float*)(z1b + (size_t)P * 64);  // [GC*128]
    float* part_p   = part_h + (size_t)GC * 128;       // [256*64]
    float* stats_h  = stats;
    float* stats_p  = stats + 128;

    float* xnew = (float*)d_out;             // [N,64]
    float* z1   = xnew + (size_t)N * 64;     // [P,64]

    hipMemsetAsync(cnt, 0, (size_t)2 * N * sizeof(int), stream);

    // Prep: conversions + transposes.
    cvt_k<<<((size_t)N * 32 / 8 + 255) / 256, 256, 0, stream>>>(x_feats, xf16,
                                                                N * 32 / 8);
    wtT_k<<<(KOFF * 32 * 64 + 255) / 256, 256, 0, stream>>>(conv1_w, wt1, 32);
    wtT_k<<<(KOFF * 64 * 64 + 255) / 256, 256, 0, stream>>>(conv2_w, wt2, 64);
    linT_k<<<8, 256, 0, stream>>>(lin_w, lwt);

    // CSR build (pslot instead of bucket).
    hist_k<<<(P + 255) / 256, 256, 0, stream>>>(p2v_idx, cnt, P);
    scan1_k<<<NB, 256, 0, stream>>>(cnt, tmp, bsum, N);
    scan2_k<<<1, 512, 0, stream>>>(bsum, bpre, NB);
    scan3_k<<<NB, 256, 0, stream>>>(cnt, tmp, bpre, off, N);
    fill_k<<<(P + 255) / 256, 256, 0, stream>>>(p2v_idx, off, cursor, pslot, P);

    // Point-branch BN stats (two-stage).
    statsp1_k<<<GP, 256, 0, stream>>>(z_feats, P, part_p);
    statsr_k<<<1, 128, 0, stream>>>(part_p, stats_p, GP, 64);

    // conv1 (MFMA) with fused BN stats: xf16 -> h2, part_h.
    convm_k<32, true><<<GC, 256, 0, stream>>>(xf16, nbr_idx, wt1, h2, part_h, N);
    statsr_k<<<1, 128, 0, stream>>>(part_h, stats_h, GC, 128);
    bnsilub_k<<<((size_t)N * 64 / 8 + 255) / 256, 256, 0, stream>>>(
        h2, stats_h, bn_gamma, bn_beta, N * 64 / 8, 1.f / (float)N);

    // conv2 (MFMA): h2 -> xb.
    convm_k<64, false><<<GC, 256, 0, stream>>>(h2, nbr_idx, wt2, xb, nullptr, N);

    // Point branch -> z1 (+ permuted bf16 copy z1b).
    point_k<<<(P + 63) / 64, 256, 0, stream>>>(xb, z_feats, interp_w, interp_idx,
                                               lwt, lin_b, stats_p, pbn_gamma,
                                               pbn_beta, pslot, z1, z1b,
                                               P, 1.f / (float)P);

    // Sequential voxel-average into x_new.
    avg_k<<<((size_t)N * 4 + 255) / 256, 256, 0, stream>>>(z1b, off, cnt, xnew, N);

    (void)n_in; (void)out_size; (void)ws_size;
}

// Round 14
// 326.447 us; speedup vs baseline: 1.0033x; 1.0033x over previous
//
#include <hip/hip_runtime.h>
#include <cstdint>

#define EPSF 1e-5f
constexpr int KOFF = 27;

typedef __attribute__((ext_vector_type(8))) short bf16x8;
typedef __attribute__((ext_vector_type(4))) float f32x4;
typedef unsigned short ushort_t;
typedef unsigned int uint_t;

// f32 -> bf16 bits, RNE
__device__ __forceinline__ ushort_t f2b(float f) {
    uint_t u = __float_as_uint(f);
    u += 0x7fffu + ((u >> 16) & 1u);
    return (ushort_t)(u >> 16);
}
// bf16 bits -> f32
__device__ __forceinline__ float b2f(ushort_t u) {
    return __uint_as_float(((uint_t)u) << 16);
}
// uint4 (8 packed bf16) -> 8 floats
__device__ __forceinline__ void u4tof(uint4 u, float* f) {
    uint_t w[4] = {u.x, u.y, u.z, u.w};
#pragma unroll
    for (int i = 0; i < 4; ++i) {
        f[2 * i]     = __uint_as_float(w[i] << 16);
        f[2 * i + 1] = __uint_as_float(w[i] & 0xffff0000u);
    }
}

__device__ __forceinline__ void gload_lds16(const void* g, float* l) {
    __builtin_amdgcn_global_load_lds(
        (const __attribute__((address_space(1))) void*)g,
        (__attribute__((address_space(3))) void*)l, 16, 0, 0);
}

// ---------------------------------------------------------------------------
// f32 -> bf16 convert, 8 elems/thread.
// ---------------------------------------------------------------------------
__global__ __launch_bounds__(256) void cvt_k(const float* __restrict__ in,
                                             ushort_t* __restrict__ out, int n8) {
    int i = blockIdx.x * 256 + threadIdx.x;
    if (i >= n8) return;
    float4 a = ((const float4*)in)[2 * i];
    float4 b = ((const float4*)in)[2 * i + 1];
    uint4 o;
    o.x = (uint_t)f2b(a.x) | ((uint_t)f2b(a.y) << 16);
    o.y = (uint_t)f2b(a.z) | ((uint_t)f2b(a.w) << 16);
    o.z = (uint_t)f2b(b.x) | ((uint_t)f2b(b.y) << 16);
    o.w = (uint_t)f2b(b.z) | ((uint_t)f2b(b.w) << 16);
    ((uint4*)out)[i] = o;
}

// W [27][CIN][64] f32 -> Wt [27][64][CIN] bf16
__global__ __launch_bounds__(256) void wtT_k(const float* __restrict__ W,
                                             ushort_t* __restrict__ Wt, int CIN) {
    int t     = blockIdx.x * 256 + threadIdx.x;
    int total = KOFF * CIN * 64;
    if (t >= total) return;
    int o    = t & 63;
    int rest = t >> 6;
    int i    = rest % CIN;
    int k    = rest / CIN;
    Wt[((size_t)k * 64 + o) * CIN + i] = f2b(W[t]);
}

// lin_w [32][64] f32 -> lin_wt [64][32] bf16
__global__ __launch_bounds__(256) void linT_k(const float* __restrict__ lw,
                                              ushort_t* __restrict__ wt) {
    int t = blockIdx.x * 256 + threadIdx.x;
    if (t >= 64 * 32) return;
    int o = t >> 5, i = t & 31;
    wt[o * 32 + i] = f2b(lw[i * 64 + o]);
}

// ---------------------------------------------------------------------------
// MFMA gather conv, PHASE-pipelined (R10 config — verified 67 us, at the
// ~2.3 TB/s random-gather service ceiling). 256 thr / 64 rows / PH=2.
// STATS=true emits per-block per-channel sum/sumsq of the bf16 outputs.
// ---------------------------------------------------------------------------
template <int CIN, bool STATS>
__global__ __launch_bounds__(256, 6) void convm_k(
    const ushort_t* __restrict__ feats,  // [N][CIN] bf16
    const int* __restrict__ nbr,         // [N][27]
    const ushort_t* __restrict__ Wt,     // [27][64][CIN] bf16
    ushort_t* __restrict__ outp,         // [N][64] bf16
    float* __restrict__ part,            // [nblocks][128] (STATS only)
    int N) {
    constexpr int CHUNKS = CIN / 8;
    constexpr int T      = CIN / 32;
    constexpr int NS     = CHUNKS / 4;
    constexpr int M      = CHUNKS - 1;
    constexpr int PH     = 2;
    constexpr int NPH    = (KOFF + PH - 1) / PH;  // 14 (last = 1 step)

    __shared__ float lds[2][PH][64 * CHUNKS * 4];

    const int lane = threadIdx.x & 63;
    const int wv   = threadIdx.x >> 6;
    const int lo   = lane & 15;
    const int hi   = lane >> 4;
    const int row0 = blockIdx.x * 64;

    int srcoff[NS];
    const int* nbp[NS];
    int ldsbase[NS];
#pragma unroll
    for (int i = 0; i < NS; ++i) {
        int c      = (wv * NS + i) * 64 + lane;
        int r      = c / CHUNKS;
        int ch     = c & M;
        srcoff[i]  = (ch ^ (r & M)) * 8;
        int grow   = row0 + r;
        if (grow >= N) grow = N - 1;
        nbp[i]     = nbr + (size_t)grow * KOFF;
        ldsbase[i] = (wv * NS + i) * 256;
    }

    f32x4 acc[4] = {{0.f, 0.f, 0.f, 0.f},
                    {0.f, 0.f, 0.f, 0.f},
                    {0.f, 0.f, 0.f, 0.f},
                    {0.f, 0.f, 0.f, 0.f}};

    int idxb[2][PH][NS];
    bf16x8 Bb[2][PH][T];

    auto NSTEPS = [&](int pp) { return (pp * PH + PH <= KOFF) ? PH : (KOFF - pp * PH); };

    auto LOADIDX = [&](int pp) {
        int ns = NSTEPS(pp);
#pragma unroll
        for (int s = 0; s < PH; ++s)
            if (s < ns)
#pragma unroll
                for (int i = 0; i < NS; ++i)
                    idxb[pp & 1][s][i] = nbp[i][pp * PH + s];
    };
    auto LOADB = [&](int pp) {
        int ns = NSTEPS(pp);
#pragma unroll
        for (int s = 0; s < PH; ++s)
            if (s < ns) {
                const ushort_t* wb =
                    Wt + ((size_t)(pp * PH + s) * 64 + wv * 16 + lo) * CIN + hi * 8;
#pragma unroll
                for (int t = 0; t < T; ++t)
                    Bb[pp & 1][s][t] = *(const bf16x8*)(wb + t * 32);
            }
    };
    auto STAGE = [&](int pp) {
        int ns = NSTEPS(pp);
#pragma unroll
        for (int s = 0; s < PH; ++s)
            if (s < ns)
#pragma unroll
                for (int i = 0; i < NS; ++i) {
                    const ushort_t* src =
                        feats + (size_t)idxb[pp & 1][s][i] * CIN + srcoff[i];
                    gload_lds16(src, &lds[pp & 1][s][ldsbase[i]]);
                }
    };

    LOADIDX(0);
    LOADIDX(1);
    LOADB(0);
    STAGE(0);
    __syncthreads();

#pragma unroll
    for (int p = 0; p < NPH; ++p) {
        if (p + 2 < NPH) LOADIDX(p + 2);
        if (p + 1 < NPH) {
            LOADB(p + 1);
            STAGE(p + 1);
        }
        __builtin_amdgcn_sched_barrier(0);
        int ns = NSTEPS(p);
#pragma unroll
        for (int s = 0; s < PH; ++s) {
            if (s < ns) {
#pragma unroll
                for (int mt = 0; mt < 4; ++mt) {
                    const int R = mt * 16 + lo;
#pragma unroll
                    for (int t = 0; t < T; ++t) {
                        int d    = t * 4 + hi;
                        int slot = d ^ (R & M);
                        bf16x8 a =
                            *(const bf16x8*)&lds[p & 1][s][(R * CHUNKS + slot) * 4];
                        acc[mt] = __builtin_amdgcn_mfma_f32_16x16x32_bf16(
                            a, Bb[p & 1][s][t], acc[mt], 0, 0, 0);
                    }
                }
            }
        }
        __syncthreads();
    }

    // C-write (+ optional fused per-block BN stats of the bf16 values).
    float s = 0.f, ss = 0.f;
#pragma unroll
    for (int mt = 0; mt < 4; ++mt) {
#pragma unroll
        for (int r = 0; r < 4; ++r) {
            int orow = row0 + mt * 16 + hi * 4 + r;
            if (orow < N) {
                ushort_t b = f2b(acc[mt][r]);
                outp[(size_t)orow * 64 + wv * 16 + lo] = b;
                if (STATS) {
                    float v = b2f(b);
                    s += v;
                    ss += v * v;
                }
            }
        }
    }
    if (STATS) {
        s  += __shfl_xor(s, 16);
        s  += __shfl_xor(s, 32);
        ss += __shfl_xor(ss, 16);
        ss += __shfl_xor(ss, 32);
        if (hi == 0) {
            part[(size_t)blockIdx.x * 128 + wv * 16 + lo]      = s;
            part[(size_t)blockIdx.x * 128 + 64 + wv * 16 + lo] = ss;
        }
    }
}

// ---------------------------------------------------------------------------
// BN stats stage 1 (f32 [n,32]): per-block partials, no atomics.
// ---------------------------------------------------------------------------
__global__ __launch_bounds__(256) void statsp1_k(const float* __restrict__ v,
                                                 int n, float* __restrict__ part) {
    __shared__ float ls[2 * 256];
    const int c = threadIdx.x & 31;
    int r0      = blockIdx.x * 8 + (threadIdx.x >> 5);
    int stride  = gridDim.x * 8;
    float s = 0.f, ss = 0.f;
    for (int r = r0; r < n; r += stride) {
        float x = v[(size_t)r * 32 + c];
        s += x;
        ss += x * x;
    }
    ls[threadIdx.x]       = s;
    ls[256 + threadIdx.x] = ss;
    __syncthreads();
    for (int off = 128; off >= 32; off >>= 1) {
        if (threadIdx.x < off) {
            ls[threadIdx.x] += ls[threadIdx.x + off];
            ls[256 + threadIdx.x] += ls[256 + threadIdx.x + off];
        }
        __syncthreads();
    }
    if (threadIdx.x < 32) {
        part[(size_t)blockIdx.x * 64 + threadIdx.x]      = ls[threadIdx.x];
        part[(size_t)blockIdx.x * 64 + 32 + threadIdx.x] = ls[256 + threadIdx.x];
    }
}

// Stage 2: out[c] = sum_g part[g][c].
__global__ __launch_bounds__(128) void statsr_k(const float* __restrict__ part,
                                                float* __restrict__ out,
                                                int G, int C2) {
    int c = threadIdx.x;
    if (c >= C2) return;
    float s = 0.f;
#pragma unroll 8
    for (int g = 0; g < G; ++g) s += part[(size_t)g * C2 + c];
    out[c] = s;
}

// BN(train)+SiLU in place over bf16 [N,64], 8 elems/thread.
__global__ __launch_bounds__(256) void bnsilub_k(ushort_t* __restrict__ h,
                                                 const float* __restrict__ stats,
                                                 const float* __restrict__ gamma,
                                                 const float* __restrict__ beta,
                                                 int total8, float invN) {
    int i8 = blockIdx.x * 256 + threadIdx.x;
    if (i8 >= total8) return;
    int c0  = (i8 * 8) & 63;
    uint4 u = ((const uint4*)h)[i8];
    float f[8];
    u4tof(u, f);
#pragma unroll
    for (int j = 0; j < 8; ++j) {
        int c     = c0 + j;
        float m   = stats[c] * invN;
        float var = stats[64 + c] * invN - m * m;
        float x   = (f[j] - m) * rsqrtf(var + EPSF) * gamma[c] + beta[c];
        f[j]      = x / (1.f + expf(-x));
    }
    uint4 o;
    o.x = (uint_t)f2b(f[0]) | ((uint_t)f2b(f[1]) << 16);
    o.y = (uint_t)f2b(f[2]) | ((uint_t)f2b(f[3]) << 16);
    o.z = (uint_t)f2b(f[4]) | ((uint_t)f2b(f[5]) << 16);
    o.w = (uint_t)f2b(f[6]) | ((uint_t)f2b(f[7]) << 16);
    ((uint4*)h)[i8] = o;
}

// ---------------------------------------------------------------------------
// Point branch (R9/R12 verified form): dedup BN+SiLU, MFMA linear, gather
// combine, f32 z1 store. No z1b (R13 regression, reverted).
// ---------------------------------------------------------------------------
__global__ __launch_bounds__(256) void point_k(
    const ushort_t* __restrict__ x,      // [N,64] bf16
    const float* __restrict__ z_feats,   // [P,32]
    const float* __restrict__ interp_w,  // [P,8]
    const int* __restrict__ interp_idx,  // [P,8]
    const ushort_t* __restrict__ lin_wt, // [64][32] bf16
    const float* __restrict__ lin_b,     // [64]
    const float* __restrict__ pstats, const float* __restrict__ pgamma,
    const float* __restrict__ pbeta, float* __restrict__ z1_out,
    int P, float invP) {
    __shared__ ushort_t pz[64 * 40];
    __shared__ float zl[64 * 68];

    const int lane = threadIdx.x & 63;
    const int wv   = threadIdx.x >> 6;
    const int lo   = lane & 15;
    const int hi   = lane >> 4;
    const int p0   = blockIdx.x * 64;

    {
        int pp = p0 + lane;
        if (pp >= P) pp = P - 1;
        const int cb      = wv;
        const float4* zr  = (const float4*)(z_feats + (size_t)pp * 32 + cb * 8);
        float4 z0 = zr[0], z1v = zr[1];
        float f[8] = {z0.x, z0.y, z0.z, z0.w, z1v.x, z1v.y, z1v.z, z1v.w};
        uint_t pk[4];
#pragma unroll
        for (int j2 = 0; j2 < 4; ++j2) {
            ushort_t lo16, hi16;
#pragma unroll
            for (int e = 0; e < 2; ++e) {
                int j     = j2 * 2 + e;
                int c     = cb * 8 + j;
                float m   = pstats[c] * invP;
                float var = pstats[32 + c] * invP - m * m;
                float zn  = (f[j] - m) * rsqrtf(var + EPSF) * pgamma[c] + pbeta[c];
                float pzv = zn / (1.f + expf(-zn));
                ushort_t b = f2b(pzv);
                if (e == 0) lo16 = b; else hi16 = b;
            }
            pk[j2] = (uint_t)lo16 | ((uint_t)hi16 << 16);
        }
        *(uint4*)&pz[lane * 40 + cb * 8] = make_uint4(pk[0], pk[1], pk[2], pk[3]);
    }
    __syncthreads();

    {
        bf16x8 a = *(const bf16x8*)&pz[(wv * 16 + lo) * 40 + hi * 8];
        f32x4 lacc[4];
#pragma unroll
        for (int nt = 0; nt < 4; ++nt) {
            bf16x8 b = *(const bf16x8*)(lin_wt + (size_t)(nt * 16 + lo) * 32 + hi * 8);
            lacc[nt] = __builtin_amdgcn_mfma_f32_16x16x32_bf16(
                a, b, (f32x4){0.f, 0.f, 0.f, 0.f}, 0, 0, 0);
        }
#pragma unroll
        for (int nt = 0; nt < 4; ++nt)
#pragma unroll
            for (int r = 0; r < 4; ++r)
                zl[(wv * 16 + hi * 4 + r) * 68 + nt * 16 + lo] = lacc[nt][r];
    }
    __syncthreads();

    const int p = p0 + lane;
    if (p >= P) return;
    const int wbase = __builtin_amdgcn_readfirstlane(wv * 16);

    const int4* iip   = (const int4*)(interp_idx + (size_t)p * 8);
    const float4* iwp = (const float4*)(interp_w + (size_t)p * 8);
    int4 ia = iip[0], ib = iip[1];
    float4 wa = iwp[0], wb = iwp[1];
    int idxs[8]  = {ia.x, ia.y, ia.z, ia.w, ib.x, ib.y, ib.z, ib.w};
    float wts[8] = {wa.x, wa.y, wa.z, wa.w, wb.x, wb.y, wb.z, wb.w};

    float acc[16];
#pragma unroll
    for (int o4 = 0; o4 < 4; ++o4) {
        f32x4 lv = *(const f32x4*)&zl[lane * 68 + wbase + o4 * 4];
#pragma unroll
        for (int j = 0; j < 4; ++j) acc[o4 * 4 + j] = lv[j];
    }

#pragma unroll
    for (int t = 0; t < 8; ++t) {
        const ushort_t* xr = x + (size_t)idxs[t] * 64 + wbase;
        float w            = wts[t];
        uint4 u0 = *(const uint4*)xr;
        uint4 u1 = *(const uint4*)(xr + 8);
        float f[16];
        u4tof(u0, f);
        u4tof(u1, f + 8);
#pragma unroll
        for (int o = 0; o < 16; ++o) acc[o] = fmaf(w, f[o], acc[o]);
    }

    const float* lb = lin_b + wbase;
#pragma unroll
    for (int o = 0; o < 16; ++o) acc[o] += lb[o];

    float* zo = z1_out + (size_t)p * 64 + wbase;
#pragma unroll
    for (int o = 0; o < 16; o += 4) {
        float4 v = {acc[o], acc[o + 1], acc[o + 2], acc[o + 3]};
        *(float4*)(zo + o) = v;
    }
}

// --------------------------- CSR build + gather-average ---------------------
__global__ __launch_bounds__(256) void hist_k(const int* __restrict__ p2v,
                                              int* __restrict__ cnt, int P) {
    int p = blockIdx.x * 256 + threadIdx.x;
    if (p < P) atomicAdd(&cnt[p2v[p]], 1);
}

__global__ __launch_bounds__(256) void scan1_k(const int* __restrict__ cnt,
                                               int* __restrict__ tmp,
                                               int* __restrict__ bsum, int n) {
    __shared__ int s[256];
    int i = blockIdx.x * 256 + threadIdx.x;
    int v = (i < n) ? cnt[i] : 0;
    s[threadIdx.x] = v;
    __syncthreads();
    for (int off = 1; off < 256; off <<= 1) {
        int t = (threadIdx.x >= off) ? s[threadIdx.x - off] : 0;
        __syncthreads();
        s[threadIdx.x] += t;
        __syncthreads();
    }
    if (i < n) tmp[i] = s[threadIdx.x];
    if (threadIdx.x == 255) bsum[blockIdx.x] = s[255];
}

// Parallel single-block scan over <=512 block sums.
__global__ __launch_bounds__(512) void scan2_k(const int* __restrict__ bsum,
                                               int* __restrict__ bpre, int nb) {
    __shared__ int s[512];
    int i = threadIdx.x;
    int v = (i < nb) ? bsum[i] : 0;
    s[i]  = v;
    __syncthreads();
    for (int off = 1; off < 512; off <<= 1) {
        int t = (i >= off) ? s[i - off] : 0;
        __syncthreads();
        s[i] += t;
        __syncthreads();
    }
    if (i < nb) bpre[i] = s[i] - v;  // exclusive
}

__global__ __launch_bounds__(256) void scan3_k(const int* __restrict__ cnt,
                                               const int* __restrict__ tmp,
                                               const int* __restrict__ bpre,
                                               int* __restrict__ off, int n) {
    int i = blockIdx.x * 256 + threadIdx.x;
    if (i < n) off[i] = bpre[i >> 8] + tmp[i] - cnt[i];
}

__global__ __launch_bounds__(256) void fill_k(const int* __restrict__ p2v,
                                              const int* __restrict__ off,
                                              int* __restrict__ cursor,
                                              int* __restrict__ bucket, int P) {
    int p = blockIdx.x * 256 + threadIdx.x;
    if (p >= P) return;
    int v    = p2v[p];
    int slot = atomicAdd(&cursor[v], 1);
    bucket[off[v] + slot] = p;
}

// x_new[v] = mean of z1 rows of points in voxel v. Thread = (voxel, quarter).
__global__ __launch_bounds__(256) void avg_k(const float* __restrict__ z1,
                                             const int* __restrict__ off,
                                             const int* __restrict__ cnt,
                                             const int* __restrict__ bucket,
                                             float* __restrict__ xnew, int N) {
    int tid = blockIdx.x * 256 + threadIdx.x;
    int v   = tid >> 2;
    if (v >= N) return;
    int q  = tid & 3;
    int c  = cnt[v];
    int st = off[v];
    float acc[16];
#pragma unroll
    for (int o = 0; o < 16; ++o) acc[o] = 0.f;
    for (int j = 0; j < c; ++j) {
        int p            = bucket[st + j];
        const float4* zr = (const float4*)(z1 + (size_t)p * 64 + q * 16);
#pragma unroll
        for (int c4 = 0; c4 < 4; ++c4) {
            float4 t = zr[c4];
            acc[c4 * 4 + 0] += t.x;
            acc[c4 * 4 + 1] += t.y;
            acc[c4 * 4 + 2] += t.z;
            acc[c4 * 4 + 3] += t.w;
        }
    }
    float rc  = 1.f / fmaxf((float)c, 1.f);
    float* op = xnew + (size_t)v * 64 + q * 16;
#pragma unroll
    for (int o = 0; o < 16; o += 4) {
        float4 t = {acc[o] * rc, acc[o + 1] * rc, acc[o + 2] * rc, acc[o + 3] * rc};
        *(float4*)(op + o) = t;
    }
}

extern "C" void kernel_launch(void* const* d_in, const int* in_sizes, int n_in,
                              void* d_out, int out_size, void* d_ws, size_t ws_size,
                              hipStream_t stream) {
    const float* x_feats   = (const float*)d_in[0];
    const float* z_feats   = (const float*)d_in[1];
    const float* interp_w  = (const float*)d_in[2];
    const int* nbr_idx     = (const int*)d_in[3];
    const int* interp_idx  = (const int*)d_in[4];
    const int* p2v_idx     = (const int*)d_in[5];
    const float* conv1_w   = (const float*)d_in[6];
    const float* conv2_w   = (const float*)d_in[7];
    const float* bn_gamma  = (const float*)d_in[8];
    const float* bn_beta   = (const float*)d_in[9];
    const float* pbn_gamma = (const float*)d_in[10];
    const float* pbn_beta  = (const float*)d_in[11];
    const float* lin_w     = (const float*)d_in[12];
    const float* lin_b     = (const float*)d_in[13];

    const int N  = in_sizes[3] / KOFF;   // 100000
    const int P  = in_sizes[5];          // 200000
    const int NB = (N + 255) / 256;
    const int GC = (N + 63) / 64;        // conv blocks (stats partials)
    const int GP = 256;

    // Workspace layout
    ushort_t* h2    = (ushort_t*)d_ws;                 // [N*64] bf16
    ushort_t* xb    = h2 + (size_t)N * 64;             // [N*64] bf16
    ushort_t* xf16  = xb + (size_t)N * 64;             // [N*32] bf16
    ushort_t* wt1   = xf16 + (size_t)N * 32;           // [27*64*32]
    ushort_t* wt2   = wt1 + KOFF * 64 * 32;            // [27*64*64]
    ushort_t* lwt   = wt2 + KOFF * 64 * 64;            // [64*32]
    int* cnt        = (int*)(lwt + 64 * 32);           // [N]
    int* cursor     = cnt + N;                         // [N]
    float* stats    = (float*)(cursor + N);            // [192]
    int* tmp        = (int*)(stats + 192);             // [N]
    int* off        = tmp + N;                         // [N]
    int* bsum       = off + N;                         // [512]
    int* bpre       = bsum + 512;                      // [512]
    int* bucket     = bpre + 512;                      // [P]
    float* part_h   = (float*)(bucket + P);            // [GC*128]
    float* part_p   = part_h + (size_t)GC * 128;       // [256*64]
    float* stats_h  = stats;
    float* stats_p  = stats + 128;

    float* xnew = (float*)d_out;             // [N,64]
    float* z1   = xnew + (size_t)N * 64;     // [P,64]

    hipMemsetAsync(cnt, 0, (size_t)2 * N * sizeof(int), stream);

    // Prep: conversions + transposes.
    cvt_k<<<((size_t)N * 32 / 8 + 255) / 256, 256, 0, stream>>>(x_feats, xf16,
                                                                N * 32 / 8);
    wtT_k<<<(KOFF * 32 * 64 + 255) / 256, 256, 0, stream>>>(conv1_w, wt1, 32);
    wtT_k<<<(KOFF * 64 * 64 + 255) / 256, 256, 0, stream>>>(conv2_w, wt2, 64);
    linT_k<<<8, 256, 0, stream>>>(lin_w, lwt);

    // CSR build.
    hist_k<<<(P + 255) / 256, 256, 0, stream>>>(p2v_idx, cnt, P);
    scan1_k<<<NB, 256, 0, stream>>>(cnt, tmp, bsum, N);
    scan2_k<<<1, 512, 0, stream>>>(bsum, bpre, NB);
    scan3_k<<<NB, 256, 0, stream>>>(cnt, tmp, bpre, off, N);
    fill_k<<<(P + 255) / 256, 256, 0, stream>>>(p2v_idx, off, cursor, bucket, P);

    // Point-branch BN stats (two-stage).
    statsp1_k<<<GP, 256, 0, stream>>>(z_feats, P, part_p);
    statsr_k<<<1, 128, 0, stream>>>(part_p, stats_p, GP, 64);

    // conv1 (MFMA) with fused BN stats: xf16 -> h2, part_h.
    convm_k<32, true><<<GC, 256, 0, stream>>>(xf16, nbr_idx, wt1, h2, part_h, N);
    statsr_k<<<1, 128, 0, stream>>>(part_h, stats_h, GC, 128);
    bnsilub_k<<<((size_t)N * 64 / 8 + 255) / 256, 256, 0, stream>>>(
        h2, stats_h, bn_gamma, bn_beta, N * 64 / 8, 1.f / (float)N);

    // conv2 (MFMA): h2 -> xb.
    convm_k<64, false><<<GC, 256, 0, stream>>>(h2, nbr_idx, wt2, xb, nullptr, N);

    // Point branch -> z1.
    point_k<<<(P + 63) / 64, 256, 0, stream>>>(xb, z_feats, interp_w, interp_idx,
                                               lwt, lin_b, stats_p, pbn_gamma,
                                               pbn_beta, z1, P, 1.f / (float)P);

    // Gather-average into x_new.
    avg_k<<<((size_t)N * 4 + 255) / 256, 256, 0, stream>>>(z1, off, cnt, bucket,
                                                           xnew, N);

    (void)n_in; (void)out_size; (void)ws_size;
}

// Round 15
// 279.780 us; speedup vs baseline: 1.1707x; 1.1668x over previous
//
#include <hip/hip_runtime.h>
#include <cstdint>

#define EPSF 1e-5f
constexpr int KOFF = 27;

typedef __attribute__((ext_vector_type(8))) short bf16x8;
typedef __attribute__((ext_vector_type(4))) float f32x4;
typedef unsigned short ushort_t;
typedef unsigned int uint_t;

// f32 -> bf16 bits, RNE
__device__ __forceinline__ ushort_t f2b(float f) {
    uint_t u = __float_as_uint(f);
    u += 0x7fffu + ((u >> 16) & 1u);
    return (ushort_t)(u >> 16);
}
// bf16 bits -> f32
__device__ __forceinline__ float b2f(ushort_t u) {
    return __uint_as_float(((uint_t)u) << 16);
}
// uint4 (8 packed bf16) -> 8 floats
__device__ __forceinline__ void u4tof(uint4 u, float* f) {
    uint_t w[4] = {u.x, u.y, u.z, u.w};
#pragma unroll
    for (int i = 0; i < 4; ++i) {
        f[2 * i]     = __uint_as_float(w[i] << 16);
        f[2 * i + 1] = __uint_as_float(w[i] & 0xffff0000u);
    }
}

__device__ __forceinline__ void gload_lds16(const void* g, float* l) {
    __builtin_amdgcn_global_load_lds(
        (const __attribute__((address_space(1))) void*)g,
        (__attribute__((address_space(3))) void*)l, 16, 0, 0);
}

// ---------------------------------------------------------------------------
// f32 -> bf16 convert, 8 elems/thread.
// ---------------------------------------------------------------------------
__global__ __launch_bounds__(256) void cvt_k(const float* __restrict__ in,
                                             ushort_t* __restrict__ out, int n8) {
    int i = blockIdx.x * 256 + threadIdx.x;
    if (i >= n8) return;
    float4 a = ((const float4*)in)[2 * i];
    float4 b = ((const float4*)in)[2 * i + 1];
    uint4 o;
    o.x = (uint_t)f2b(a.x) | ((uint_t)f2b(a.y) << 16);
    o.y = (uint_t)f2b(a.z) | ((uint_t)f2b(a.w) << 16);
    o.z = (uint_t)f2b(b.x) | ((uint_t)f2b(b.y) << 16);
    o.w = (uint_t)f2b(b.z) | ((uint_t)f2b(b.w) << 16);
    ((uint4*)out)[i] = o;
}

// W [27][CIN][64] f32 -> Wt [27][64][CIN] bf16
__global__ __launch_bounds__(256) void wtT_k(const float* __restrict__ W,
                                             ushort_t* __restrict__ Wt, int CIN) {
    int t     = blockIdx.x * 256 + threadIdx.x;
    int total = KOFF * CIN * 64;
    if (t >= total) return;
    int o    = t & 63;
    int rest = t >> 6;
    int i    = rest % CIN;
    int k    = rest / CIN;
    Wt[((size_t)k * 64 + o) * CIN + i] = f2b(W[t]);
}

// lin_w [32][64] f32 -> lin_wt [64][32] bf16
__global__ __launch_bounds__(256) void linT_k(const float* __restrict__ lw,
                                              ushort_t* __restrict__ wt) {
    int t = blockIdx.x * 256 + threadIdx.x;
    if (t >= 64 * 32) return;
    int o = t >> 5, i = t & 31;
    wt[o * 32 + i] = f2b(lw[i * 64 + o]);
}

// ---------------------------------------------------------------------------
// MFMA gather conv, PHASE-pipelined (R10 config — verified 67 us, at the
// ~2.3 TB/s random-gather service ceiling). 256 thr / 64 rows / PH=2.
// STATS=true emits per-block per-channel sum/sumsq of the bf16 outputs.
// ---------------------------------------------------------------------------
template <int CIN, bool STATS>
__global__ __launch_bounds__(256, 6) void convm_k(
    const ushort_t* __restrict__ feats,  // [N][CIN] bf16
    const int* __restrict__ nbr,         // [N][27]
    const ushort_t* __restrict__ Wt,     // [27][64][CIN] bf16
    ushort_t* __restrict__ outp,         // [N][64] bf16
    float* __restrict__ part,            // [nblocks][128] (STATS only)
    int N) {
    constexpr int CHUNKS = CIN / 8;
    constexpr int T      = CIN / 32;
    constexpr int NS     = CHUNKS / 4;
    constexpr int M      = CHUNKS - 1;
    constexpr int PH     = 2;
    constexpr int NPH    = (KOFF + PH - 1) / PH;  // 14 (last = 1 step)

    __shared__ float lds[2][PH][64 * CHUNKS * 4];

    const int lane = threadIdx.x & 63;
    const int wv   = threadIdx.x >> 6;
    const int lo   = lane & 15;
    const int hi   = lane >> 4;
    const int row0 = blockIdx.x * 64;

    int srcoff[NS];
    const int* nbp[NS];
    int ldsbase[NS];
#pragma unroll
    for (int i = 0; i < NS; ++i) {
        int c      = (wv * NS + i) * 64 + lane;
        int r      = c / CHUNKS;
        int ch     = c & M;
        srcoff[i]  = (ch ^ (r & M)) * 8;
        int grow   = row0 + r;
        if (grow >= N) grow = N - 1;
        nbp[i]     = nbr + (size_t)grow * KOFF;
        ldsbase[i] = (wv * NS + i) * 256;
    }

    f32x4 acc[4] = {{0.f, 0.f, 0.f, 0.f},
                    {0.f, 0.f, 0.f, 0.f},
                    {0.f, 0.f, 0.f, 0.f},
                    {0.f, 0.f, 0.f, 0.f}};

    int idxb[2][PH][NS];
    bf16x8 Bb[2][PH][T];

    auto NSTEPS = [&](int pp) { return (pp * PH + PH <= KOFF) ? PH : (KOFF - pp * PH); };

    auto LOADIDX = [&](int pp) {
        int ns = NSTEPS(pp);
#pragma unroll
        for (int s = 0; s < PH; ++s)
            if (s < ns)
#pragma unroll
                for (int i = 0; i < NS; ++i)
                    idxb[pp & 1][s][i] = nbp[i][pp * PH + s];
    };
    auto LOADB = [&](int pp) {
        int ns = NSTEPS(pp);
#pragma unroll
        for (int s = 0; s < PH; ++s)
            if (s < ns) {
                const ushort_t* wb =
                    Wt + ((size_t)(pp * PH + s) * 64 + wv * 16 + lo) * CIN + hi * 8;
#pragma unroll
                for (int t = 0; t < T; ++t)
                    Bb[pp & 1][s][t] = *(const bf16x8*)(wb + t * 32);
            }
    };
    auto STAGE = [&](int pp) {
        int ns = NSTEPS(pp);
#pragma unroll
        for (int s = 0; s < PH; ++s)
            if (s < ns)
#pragma unroll
                for (int i = 0; i < NS; ++i) {
                    const ushort_t* src =
                        feats + (size_t)idxb[pp & 1][s][i] * CIN + srcoff[i];
                    gload_lds16(src, &lds[pp & 1][s][ldsbase[i]]);
                }
    };

    LOADIDX(0);
    LOADIDX(1);
    LOADB(0);
    STAGE(0);
    __syncthreads();

#pragma unroll
    for (int p = 0; p < NPH; ++p) {
        if (p + 2 < NPH) LOADIDX(p + 2);
        if (p + 1 < NPH) {
            LOADB(p + 1);
            STAGE(p + 1);
        }
        __builtin_amdgcn_sched_barrier(0);
        int ns = NSTEPS(p);
#pragma unroll
        for (int s = 0; s < PH; ++s) {
            if (s < ns) {
#pragma unroll
                for (int mt = 0; mt < 4; ++mt) {
                    const int R = mt * 16 + lo;
#pragma unroll
                    for (int t = 0; t < T; ++t) {
                        int d    = t * 4 + hi;
                        int slot = d ^ (R & M);
                        bf16x8 a =
                            *(const bf16x8*)&lds[p & 1][s][(R * CHUNKS + slot) * 4];
                        acc[mt] = __builtin_amdgcn_mfma_f32_16x16x32_bf16(
                            a, Bb[p & 1][s][t], acc[mt], 0, 0, 0);
                    }
                }
            }
        }
        __syncthreads();
    }

    // C-write (+ optional fused per-block BN stats of the bf16 values).
    float s = 0.f, ss = 0.f;
#pragma unroll
    for (int mt = 0; mt < 4; ++mt) {
#pragma unroll
        for (int r = 0; r < 4; ++r) {
            int orow = row0 + mt * 16 + hi * 4 + r;
            if (orow < N) {
                ushort_t b = f2b(acc[mt][r]);
                outp[(size_t)orow * 64 + wv * 16 + lo] = b;
                if (STATS) {
                    float v = b2f(b);
                    s += v;
                    ss += v * v;
                }
            }
        }
    }
    if (STATS) {
        s  += __shfl_xor(s, 16);
        s  += __shfl_xor(s, 32);
        ss += __shfl_xor(ss, 16);
        ss += __shfl_xor(ss, 32);
        if (hi == 0) {
            part[(size_t)blockIdx.x * 128 + wv * 16 + lo]      = s;
            part[(size_t)blockIdx.x * 128 + 64 + wv * 16 + lo] = ss;
        }
    }
}

// ---------------------------------------------------------------------------
// BN stats stage 1 (f32 [n,32]): per-block partials, no atomics.
// ---------------------------------------------------------------------------
__global__ __launch_bounds__(256) void statsp1_k(const float* __restrict__ v,
                                                 int n, float* __restrict__ part) {
    __shared__ float ls[2 * 256];
    const int c = threadIdx.x & 31;
    int r0      = blockIdx.x * 8 + (threadIdx.x >> 5);
    int stride  = gridDim.x * 8;
    float s = 0.f, ss = 0.f;
    for (int r = r0; r < n; r += stride) {
        float x = v[(size_t)r * 32 + c];
        s += x;
        ss += x * x;
    }
    ls[threadIdx.x]       = s;
    ls[256 + threadIdx.x] = ss;
    __syncthreads();
    for (int off = 128; off >= 32; off >>= 1) {
        if (threadIdx.x < off) {
            ls[threadIdx.x] += ls[threadIdx.x + off];
            ls[256 + threadIdx.x] += ls[256 + threadIdx.x + off];
        }
        __syncthreads();
    }
    if (threadIdx.x < 32) {
        part[(size_t)blockIdx.x * 64 + threadIdx.x]      = ls[threadIdx.x];
        part[(size_t)blockIdx.x * 64 + 32 + threadIdx.x] = ls[256 + threadIdx.x];
    }
}

// Stage 2a: parallel tree step — block b sums groups g = b, b+32, ...
// (coalesced row reads). part2[b][C2].
template <int C2>
__global__ __launch_bounds__(C2) void statsr1_k(const float* __restrict__ part,
                                                float* __restrict__ part2, int G) {
    int c = threadIdx.x;
    int b = blockIdx.x;  // 0..31
    float s = 0.f;
    for (int g = b; g < G; g += 32) s += part[(size_t)g * C2 + c];
    part2[(size_t)b * C2 + c] = s;
}

// Stage 2b: out[c] = sum_g part[g][c] (small G).
__global__ __launch_bounds__(128) void statsr_k(const float* __restrict__ part,
                                                float* __restrict__ out,
                                                int G, int C2) {
    int c = threadIdx.x;
    if (c >= C2) return;
    float s = 0.f;
#pragma unroll 8
    for (int g = 0; g < G; ++g) s += part[(size_t)g * C2 + c];
    out[c] = s;
}

// BN(train)+SiLU in place over bf16 [N,64], 8 elems/thread.
__global__ __launch_bounds__(256) void bnsilub_k(ushort_t* __restrict__ h,
                                                 const float* __restrict__ stats,
                                                 const float* __restrict__ gamma,
                                                 const float* __restrict__ beta,
                                                 int total8, float invN) {
    int i8 = blockIdx.x * 256 + threadIdx.x;
    if (i8 >= total8) return;
    int c0  = (i8 * 8) & 63;
    uint4 u = ((const uint4*)h)[i8];
    float f[8];
    u4tof(u, f);
#pragma unroll
    for (int j = 0; j < 8; ++j) {
        int c     = c0 + j;
        float m   = stats[c] * invN;
        float var = stats[64 + c] * invN - m * m;
        float x   = (f[j] - m) * rsqrtf(var + EPSF) * gamma[c] + beta[c];
        f[j]      = x / (1.f + expf(-x));
    }
    uint4 o;
    o.x = (uint_t)f2b(f[0]) | ((uint_t)f2b(f[1]) << 16);
    o.y = (uint_t)f2b(f[2]) | ((uint_t)f2b(f[3]) << 16);
    o.z = (uint_t)f2b(f[4]) | ((uint_t)f2b(f[5]) << 16);
    o.w = (uint_t)f2b(f[6]) | ((uint_t)f2b(f[7]) << 16);
    ((uint4*)h)[i8] = o;
}

// ---------------------------------------------------------------------------
// Point branch (R9/R12 verified form): dedup BN+SiLU, MFMA linear, gather
// combine, f32 z1 store.
// ---------------------------------------------------------------------------
__global__ __launch_bounds__(256) void point_k(
    const ushort_t* __restrict__ x,      // [N,64] bf16
    const float* __restrict__ z_feats,   // [P,32]
    const float* __restrict__ interp_w,  // [P,8]
    const int* __restrict__ interp_idx,  // [P,8]
    const ushort_t* __restrict__ lin_wt, // [64][32] bf16
    const float* __restrict__ lin_b,     // [64]
    const float* __restrict__ pstats, const float* __restrict__ pgamma,
    const float* __restrict__ pbeta, float* __restrict__ z1_out,
    int P, float invP) {
    __shared__ ushort_t pz[64 * 40];
    __shared__ float zl[64 * 68];

    const int lane = threadIdx.x & 63;
    const int wv   = threadIdx.x >> 6;
    const int lo   = lane & 15;
    const int hi   = lane >> 4;
    const int p0   = blockIdx.x * 64;

    {
        int pp = p0 + lane;
        if (pp >= P) pp = P - 1;
        const int cb      = wv;
        const float4* zr  = (const float4*)(z_feats + (size_t)pp * 32 + cb * 8);
        float4 z0 = zr[0], z1v = zr[1];
        float f[8] = {z0.x, z0.y, z0.z, z0.w, z1v.x, z1v.y, z1v.z, z1v.w};
        uint_t pk[4];
#pragma unroll
        for (int j2 = 0; j2 < 4; ++j2) {
            ushort_t lo16, hi16;
#pragma unroll
            for (int e = 0; e < 2; ++e) {
                int j     = j2 * 2 + e;
                int c     = cb * 8 + j;
                float m   = pstats[c] * invP;
                float var = pstats[32 + c] * invP - m * m;
                float zn  = (f[j] - m) * rsqrtf(var + EPSF) * pgamma[c] + pbeta[c];
                float pzv = zn / (1.f + expf(-zn));
                ushort_t b = f2b(pzv);
                if (e == 0) lo16 = b; else hi16 = b;
            }
            pk[j2] = (uint_t)lo16 | ((uint_t)hi16 << 16);
        }
        *(uint4*)&pz[lane * 40 + cb * 8] = make_uint4(pk[0], pk[1], pk[2], pk[3]);
    }
    __syncthreads();

    {
        bf16x8 a = *(const bf16x8*)&pz[(wv * 16 + lo) * 40 + hi * 8];
        f32x4 lacc[4];
#pragma unroll
        for (int nt = 0; nt < 4; ++nt) {
            bf16x8 b = *(const bf16x8*)(lin_wt + (size_t)(nt * 16 + lo) * 32 + hi * 8);
            lacc[nt] = __builtin_amdgcn_mfma_f32_16x16x32_bf16(
                a, b, (f32x4){0.f, 0.f, 0.f, 0.f}, 0, 0, 0);
        }
#pragma unroll
        for (int nt = 0; nt < 4; ++nt)
#pragma unroll
            for (int r = 0; r < 4; ++r)
                zl[(wv * 16 + hi * 4 + r) * 68 + nt * 16 + lo] = lacc[nt][r];
    }
    __syncthreads();

    const int p = p0 + lane;
    if (p >= P) return;
    const int wbase = __builtin_amdgcn_readfirstlane(wv * 16);

    const int4* iip   = (const int4*)(interp_idx + (size_t)p * 8);
    const float4* iwp = (const float4*)(interp_w + (size_t)p * 8);
    int4 ia = iip[0], ib = iip[1];
    float4 wa = iwp[0], wb = iwp[1];
    int idxs[8]  = {ia.x, ia.y, ia.z, ia.w, ib.x, ib.y, ib.z, ib.w};
    float wts[8] = {wa.x, wa.y, wa.z, wa.w, wb.x, wb.y, wb.z, wb.w};

    float acc[16];
#pragma unroll
    for (int o4 = 0; o4 < 4; ++o4) {
        f32x4 lv = *(const f32x4*)&zl[lane * 68 + wbase + o4 * 4];
#pragma unroll
        for (int j = 0; j < 4; ++j) acc[o4 * 4 + j] = lv[j];
    }

#pragma unroll
    for (int t = 0; t < 8; ++t) {
        const ushort_t* xr = x + (size_t)idxs[t] * 64 + wbase;
        float w            = wts[t];
        uint4 u0 = *(const uint4*)xr;
        uint4 u1 = *(const uint4*)(xr + 8);
        float f[16];
        u4tof(u0, f);
        u4tof(u1, f + 8);
#pragma unroll
        for (int o = 0; o < 16; ++o) acc[o] = fmaf(w, f[o], acc[o]);
    }

    const float* lb = lin_b + wbase;
#pragma unroll
    for (int o = 0; o < 16; ++o) acc[o] += lb[o];

    float* zo = z1_out + (size_t)p * 64 + wbase;
#pragma unroll
    for (int o = 0; o < 16; o += 4) {
        float4 v = {acc[o], acc[o + 1], acc[o + 2], acc[o + 3]};
        *(float4*)(zo + o) = v;
    }
}

// --------------------------- CSR build + gather-average ---------------------
__global__ __launch_bounds__(256) void hist_k(const int* __restrict__ p2v,
                                              int* __restrict__ cnt, int P) {
    int p = blockIdx.x * 256 + threadIdx.x;
    if (p < P) atomicAdd(&cnt[p2v[p]], 1);
}

__global__ __launch_bounds__(256) void scan1_k(const int* __restrict__ cnt,
                                               int* __restrict__ tmp,
                                               int* __restrict__ bsum, int n) {
    __shared__ int s[256];
    int i = blockIdx.x * 256 + threadIdx.x;
    int v = (i < n) ? cnt[i] : 0;
    s[threadIdx.x] = v;
    __syncthreads();
    for (int off = 1; off < 256; off <<= 1) {
        int t = (threadIdx.x >= off) ? s[threadIdx.x - off] : 0;
        __syncthreads();
        s[threadIdx.x] += t;
        __syncthreads();
    }
    if (i < n) tmp[i] = s[threadIdx.x];
    if (threadIdx.x == 255) bsum[blockIdx.x] = s[255];
}

// Parallel single-block scan over <=512 block sums.
__global__ __launch_bounds__(512) void scan2_k(const int* __restrict__ bsum,
                                               int* __restrict__ bpre, int nb) {
    __shared__ int s[512];
    int i = threadIdx.x;
    int v = (i < nb) ? bsum[i] : 0;
    s[i]  = v;
    __syncthreads();
    for (int off = 1; off < 512; off <<= 1) {
        int t = (i >= off) ? s[i - off] : 0;
        __syncthreads();
        s[i] += t;
        __syncthreads();
    }
    if (i < nb) bpre[i] = s[i] - v;  // exclusive
}

__global__ __launch_bounds__(256) void scan3_k(const int* __restrict__ cnt,
                                               const int* __restrict__ tmp,
                                               const int* __restrict__ bpre,
                                               int* __restrict__ off, int n) {
    int i = blockIdx.x * 256 + threadIdx.x;
    if (i < n) off[i] = bpre[i >> 8] + tmp[i] - cnt[i];
}

__global__ __launch_bounds__(256) void fill_k(const int* __restrict__ p2v,
                                              const int* __restrict__ off,
                                              int* __restrict__ cursor,
                                              int* __restrict__ bucket, int P) {
    int p = blockIdx.x * 256 + threadIdx.x;
    if (p >= P) return;
    int v    = p2v[p];
    int slot = atomicAdd(&cursor[v], 1);
    bucket[off[v] + slot] = p;
}

// x_new[v] = mean of z1 rows of points in voxel v. Thread = (voxel, quarter).
__global__ __launch_bounds__(256) void avg_k(const float* __restrict__ z1,
                                             const int* __restrict__ off,
                                             const int* __restrict__ cnt,
                                             const int* __restrict__ bucket,
                                             float* __restrict__ xnew, int N) {
    int tid = blockIdx.x * 256 + threadIdx.x;
    int v   = tid >> 2;
    if (v >= N) return;
    int q  = tid & 3;
    int c  = cnt[v];
    int st = off[v];
    float acc[16];
#pragma unroll
    for (int o = 0; o < 16; ++o) acc[o] = 0.f;
    for (int j = 0; j < c; ++j) {
        int p            = bucket[st + j];
        const float4* zr = (const float4*)(z1 + (size_t)p * 64 + q * 16);
#pragma unroll
        for (int c4 = 0; c4 < 4; ++c4) {
            float4 t = zr[c4];
            acc[c4 * 4 + 0] += t.x;
            acc[c4 * 4 + 1] += t.y;
            acc[c4 * 4 + 2] += t.z;
            acc[c4 * 4 + 3] += t.w;
        }
    }
    float rc  = 1.f / fmaxf((float)c, 1.f);
    float* op = xnew + (size_t)v * 64 + q * 16;
#pragma unroll
    for (int o = 0; o < 16; o += 4) {
        float4 t = {acc[o] * rc, acc[o + 1] * rc, acc[o + 2] * rc, acc[o + 3] * rc};
        *(float4*)(op + o) = t;
    }
}

extern "C" void kernel_launch(void* const* d_in, const int* in_sizes, int n_in,
                              void* d_out, int out_size, void* d_ws, size_t ws_size,
                              hipStream_t stream) {
    const float* x_feats   = (const float*)d_in[0];
    const float* z_feats   = (const float*)d_in[1];
    const float* interp_w  = (const float*)d_in[2];
    const int* nbr_idx     = (const int*)d_in[3];
    const int* interp_idx  = (const int*)d_in[4];
    const int* p2v_idx     = (const int*)d_in[5];
    const float* conv1_w   = (const float*)d_in[6];
    const float* conv2_w   = (const float*)d_in[7];
    const float* bn_gamma  = (const float*)d_in[8];
    const float* bn_beta   = (const float*)d_in[9];
    const float* pbn_gamma = (const float*)d_in[10];
    const float* pbn_beta  = (const float*)d_in[11];
    const float* lin_w     = (const float*)d_in[12];
    const float* lin_b     = (const float*)d_in[13];

    const int N  = in_sizes[3] / KOFF;   // 100000
    const int P  = in_sizes[5];          // 200000
    const int NB = (N + 255) / 256;
    const int GC = (N + 63) / 64;        // conv blocks (stats partials)
    const int GP = 256;

    // Workspace layout
    ushort_t* h2    = (ushort_t*)d_ws;                 // [N*64] bf16
    ushort_t* xb    = h2 + (size_t)N * 64;             // [N*64] bf16
    ushort_t* xf16  = xb + (size_t)N * 64;             // [N*32] bf16
    ushort_t* wt1   = xf16 + (size_t)N * 32;           // [27*64*32]
    ushort_t* wt2   = wt1 + KOFF * 64 * 32;            // [27*64*64]
    ushort_t* lwt   = wt2 + KOFF * 64 * 64;            // [64*32]
    int* cnt        = (int*)(lwt + 64 * 32);           // [N]
    int* cursor     = cnt + N;                         // [N]
    float* stats    = (float*)(cursor + N);            // [192]
    int* tmp        = (int*)(stats + 192);             // [N]
    int* off        = tmp + N;                         // [N]
    int* bsum       = off + N;                         // [512]
    int* bpre       = bsum + 512;                      // [512]
    int* bucket     = bpre + 512;                      // [P]
    float* part_h   = (float*)(bucket + P);            // [GC*128]
    float* part_p   = part_h + (size_t)GC * 128;       // [256*64]
    float* part2_h  = part_p + (size_t)GP * 64;        // [32*128]
    float* part2_p  = part2_h + 32 * 128;              // [32*64]
    float* stats_h  = stats;
    float* stats_p  = stats + 128;

    float* xnew = (float*)d_out;             // [N,64]
    float* z1   = xnew + (size_t)N * 64;     // [P,64]

    hipMemsetAsync(cnt, 0, (size_t)2 * N * sizeof(int), stream);

    // Prep: conversions + transposes.
    cvt_k<<<((size_t)N * 32 / 8 + 255) / 256, 256, 0, stream>>>(x_feats, xf16,
                                                                N * 32 / 8);
    wtT_k<<<(KOFF * 32 * 64 + 255) / 256, 256, 0, stream>>>(conv1_w, wt1, 32);
    wtT_k<<<(KOFF * 64 * 64 + 255) / 256, 256, 0, stream>>>(conv2_w, wt2, 64);
    linT_k<<<8, 256, 0, stream>>>(lin_w, lwt);

    // CSR build.
    hist_k<<<(P + 255) / 256, 256, 0, stream>>>(p2v_idx, cnt, P);
    scan1_k<<<NB, 256, 0, stream>>>(cnt, tmp, bsum, N);
    scan2_k<<<1, 512, 0, stream>>>(bsum, bpre, NB);
    scan3_k<<<NB, 256, 0, stream>>>(cnt, tmp, bpre, off, N);
    fill_k<<<(P + 255) / 256, 256, 0, stream>>>(p2v_idx, off, cursor, bucket, P);

    // Point-branch BN stats (two-stage tree).
    statsp1_k<<<GP, 256, 0, stream>>>(z_feats, P, part_p);
    statsr1_k<64><<<32, 64, 0, stream>>>(part_p, part2_p, GP);
    statsr_k<<<1, 128, 0, stream>>>(part2_p, stats_p, 32, 64);

    // conv1 (MFMA) with fused BN stats: xf16 -> h2, part_h.
    convm_k<32, true><<<GC, 256, 0, stream>>>(xf16, nbr_idx, wt1, h2, part_h, N);
    statsr1_k<128><<<32, 128, 0, stream>>>(part_h, part2_h, GC);
    statsr_k<<<1, 128, 0, stream>>>(part2_h, stats_h, 32, 128);
    bnsilub_k<<<((size_t)N * 64 / 8 + 255) / 256, 256, 0, stream>>>(
        h2, stats_h, bn_gamma, bn_beta, N * 64 / 8, 1.f / (float)N);

    // conv2 (MFMA): h2 -> xb.
    convm_k<64, false><<<GC, 256, 0, stream>>>(h2, nbr_idx, wt2, xb, nullptr, N);

    // Point branch -> z1.
    point_k<<<(P + 63) / 64, 256, 0, stream>>>(xb, z_feats, interp_w, interp_idx,
                                               lwt, lin_b, stats_p, pbn_gamma,
                                               pbn_beta, z1, P, 1.f / (float)P);

    // Gather-average into x_new.
    avg_k<<<((size_t)N * 4 + 255) / 256, 256, 0, stream>>>(z1, off, cnt, bucket,
                                                           xnew, N);

    (void)n_in; (void)out_size; (void)ws_size;
}